// Round 11
// baseline (577.481 us; speedup 1.0000x reference)
//
#include <hip/hip_runtime.h>
#include <math.h>

#define N_NODES 100000
#define E_EDGES 1600000
#define E_TOT   (E_EDGES + N_NODES)
#define G_GRAPHS 64
#define IN_DIM 256
#define HID 64
#define HEADS 4
#define D1 256            // HEADS*HID
#define NEG_SLOPE 0.2f
#define SCAN_B 1024

typedef float nfloat4 __attribute__((ext_vector_type(4)));
typedef unsigned short nus4 __attribute__((ext_vector_type(4)));
typedef short bf16x8 __attribute__((ext_vector_type(8)));
typedef float f32x4 __attribute__((ext_vector_type(4)));

// bf16 <-> fp32
__device__ __forceinline__ float bf2f(unsigned short u) {
    unsigned int t = ((unsigned int)u) << 16;
    return __builtin_bit_cast(float, t);
}
__device__ __forceinline__ unsigned short f2bf(float f) {
    unsigned int u = __builtin_bit_cast(unsigned int, f);
    u += 0x7FFF + ((u >> 16) & 1);
    return (unsigned short)(u >> 16);
}
// pack 2 fp32 -> 2 bf16 in one dword (add-0x8000 round + v_perm)
__device__ __forceinline__ unsigned int pk2(float lo, float hi) {
    unsigned int ul = __builtin_bit_cast(unsigned int, lo) + 0x8000u;
    unsigned int uh = __builtin_bit_cast(unsigned int, hi) + 0x8000u;
    return __builtin_amdgcn_perm(uh, ul, 0x07060302u);
}

// ---------------- weight pre-pack (both layers, ONE launch) ----------------
__device__ __forceinline__ void packW(const float* __restrict__ W,
                                      unsigned short* __restrict__ Wpk, int Nc, int t)
{
    int kg = t / Nc, n = t - kg * Nc;
    const float* p = W + (size_t)(kg * 8) * Nc + n;
    uint4 v;
    v.x = pk2(p[0],      p[Nc]);
    v.y = pk2(p[2 * Nc], p[3 * Nc]);
    v.z = pk2(p[4 * Nc], p[5 * Nc]);
    v.w = pk2(p[6 * Nc], p[7 * Nc]);
    *(uint4*)(Wpk + (size_t)t * 8) = v;
}
__global__ __launch_bounds__(256) void convW2x(const float* __restrict__ W1,
                                               unsigned short* __restrict__ Wpk1,
                                               const float* __restrict__ W2,
                                               unsigned short* __restrict__ Wpk2)
{
    int t = blockIdx.x * 256 + threadIdx.x;
    if (t < 32 * D1) packW(W1, Wpk1, D1, t);
    else if (t < 32 * D1 + 32 * HID) packW(W2, Wpk2, HID, t - 32 * D1);
}

// ---------------- barrier-free direct MFMA GEMM, column-split across waves ----------------
// Wave = 16 rows x NCW cols (NCW=64 -> acc 16 AGPR, 4 B-loads + 4 MFMA + 1 A-load
// per k-step, ~8 waves/SIMD). B from L2-resident Wpk; A straight from global (x is
// L3-resident). No LDS, no barriers. Same k/cg accumulation order -> bit-identical.
// CFP8: C stored fp8 e4m3; else bf16.
template<int NC, int NCW, bool ABF16, bool CFP8>
__global__ __launch_bounds__(256) void gemm_direct(const void* __restrict__ Ain,
                                                   const unsigned short* __restrict__ Wpk,
                                                   void* __restrict__ C,
                                                   const float* __restrict__ att_src,
                                                   const float* __restrict__ att_dst,
                                                   float* __restrict__ a_srcO,
                                                   float* __restrict__ a_dstO,
                                                   int astride)
{
    constexpr int NCG = NCW / 16;
    const int lane = threadIdx.x & 63, wv = threadIdx.x >> 6;
    const int qd = lane >> 4, c16 = lane & 15;
    const int r0 = blockIdx.x * 64 + wv * 16;     // wave's 16 output rows
    const int bn = blockIdx.y * NCW;               // wave's column group
    const int gm = r0 + c16;                       // A row this lane loads
    const bool mv = gm < N_NODES;

    f32x4 acc[NCG];
#pragma unroll
    for (int j = 0; j < NCG; ++j) acc[j] = (f32x4){0.f, 0.f, 0.f, 0.f};

    // A prefetch regs (lane holds A[gm][k0+qd*8 .. +7])
    uint4 ua;
    float4 fa0, fa1;
    if (ABF16) {
        const unsigned short* Ab = (const unsigned short*)Ain + (size_t)gm * 256 + qd * 8;
        ua = mv ? *(const uint4*)Ab : make_uint4(0, 0, 0, 0);
    } else {
        const float* Af = (const float*)Ain + (size_t)gm * 256 + qd * 8;
        if (mv) { fa0 = ((const float4*)Af)[0]; fa1 = ((const float4*)Af)[1]; }
        else { fa0 = fa1 = make_float4(0.f, 0.f, 0.f, 0.f); }
    }

    for (int k0 = 0; k0 < 256; k0 += 32) {
        bf16x8 af;
        if (ABF16) {
            af = __builtin_bit_cast(bf16x8, ua);
        } else {
            uint4 w;
            w.x = pk2(fa0.x, fa0.y); w.y = pk2(fa0.z, fa0.w);
            w.z = pk2(fa1.x, fa1.y); w.w = pk2(fa1.z, fa1.w);
            af = __builtin_bit_cast(bf16x8, w);
        }
        if (k0 + 32 < 256) {                       // prefetch next A k-chunk
            if (ABF16) {
                const unsigned short* Ab = (const unsigned short*)Ain + (size_t)gm * 256 + (k0 + 32) + qd * 8;
                ua = mv ? *(const uint4*)Ab : make_uint4(0, 0, 0, 0);
            } else {
                const float* Af = (const float*)Ain + (size_t)gm * 256 + (k0 + 32) + qd * 8;
                if (mv) { fa0 = ((const float4*)Af)[0]; fa1 = ((const float4*)Af)[1]; }
            }
        }
        const unsigned short* Wq = Wpk + ((size_t)((k0 >> 3) + qd) * NC + bn) * 8;
#pragma unroll
        for (int cg = 0; cg < NCG; ++cg) {
            bf16x8 bfr = *(const bf16x8*)(Wq + (size_t)(cg * 16 + c16) * 8);
            acc[cg] = __builtin_amdgcn_mfma_f32_16x16x32_bf16(af, bfr, acc[cg], 0, 0, 0);
        }
    }

    // ---- epilogue: attention dots (fp32 acc, exact) + C store ----
    float sv[NCG], dv[NCG];
#pragma unroll
    for (int cg = 0; cg < NCG; ++cg) {
        sv[cg] = att_src[bn + cg * 16 + c16];
        dv[cg] = att_dst[bn + cg * 16 + c16];
    }
#pragma unroll
    for (int reg = 0; reg < 4; ++reg) {
        const int m = r0 + qd * 4 + reg;
#pragma unroll
        for (int hh = 0; hh < NCG / 4; ++hh) {
            float ps = 0.f, pd = 0.f;
#pragma unroll
            for (int cg = 4 * hh; cg < 4 * hh + 4; ++cg) {
                ps += acc[cg][reg] * sv[cg];
                pd += acc[cg][reg] * dv[cg];
            }
#pragma unroll
            for (int o = 1; o < 16; o <<= 1) { ps += __shfl_xor(ps, o); pd += __shfl_xor(pd, o); }
            if (c16 == 0 && m < N_NODES) {
                a_srcO[m * astride + (bn >> 6) + hh] = ps;
                a_dstO[m * astride + (bn >> 6) + hh] = pd;
            }
        }
        if (m < N_NODES) {
#pragma unroll
            for (int cg = 0; cg < NCG; ++cg) {
                float val = acc[cg][reg];
                if (CFP8) {
                    unsigned int q8 = (unsigned int)__builtin_amdgcn_cvt_pk_fp8_f32(val, val, 0, false);
                    ((unsigned char*)C)[(size_t)m * NC + bn + cg * 16 + c16] = (unsigned char)q8;
                } else {
                    ((unsigned short*)C)[(size_t)m * NC + bn + cg * 16 + c16] = f2bf(val);
                }
            }
        }
    }
}

// ---------------- CSR build: histogram(+rank), scan, atomic-free scatter ----------------
__global__ void edge_hist(const int* __restrict__ ei, int* __restrict__ deg,
                          int* __restrict__ rank)
{
    for (int e = blockIdx.x * blockDim.x + threadIdx.x; e < E_TOT; e += gridDim.x * blockDim.x) {
        int d = (e < E_EDGES) ? ei[E_EDGES + e] : (e - E_EDGES);
        rank[e] = atomicAdd(&deg[d], 1);
    }
}

__global__ __launch_bounds__(SCAN_B) void scan_block(const int* __restrict__ deg,
                                                     int* __restrict__ incl,
                                                     int* __restrict__ bsum, int n)
{
    __shared__ int s[SCAN_B];
    int i = blockIdx.x * SCAN_B + threadIdx.x;
    int v = (i < n) ? deg[i] : 0;
    s[threadIdx.x] = v;
    __syncthreads();
    for (int off = 1; off < SCAN_B; off <<= 1) {
        int t = (threadIdx.x >= off) ? s[threadIdx.x - off] : 0;
        __syncthreads();
        s[threadIdx.x] += t;
        __syncthreads();
    }
    if (i < n) incl[i] = s[threadIdx.x];
    if (threadIdx.x == SCAN_B - 1) bsum[blockIdx.x] = s[SCAN_B - 1];
}

__global__ void scan_bsum(const int* __restrict__ bsum, int* __restrict__ bex, int nb)
{
    __shared__ int s[128];
    int i = threadIdx.x;
    int v = (i < nb) ? bsum[i] : 0;
    s[i] = v;
    __syncthreads();
    for (int off = 1; off < 128; off <<= 1) {
        int t = (i >= off) ? s[i - off] : 0;
        __syncthreads();
        s[i] += t;
        __syncthreads();
    }
    if (i < nb) bex[i] = s[i] - v;   // exclusive
}

__global__ void finalize_off(const int* __restrict__ deg, const int* __restrict__ incl,
                             const int* __restrict__ bex, int* __restrict__ off, int n)
{
    int i = blockIdx.x * blockDim.x + threadIdx.x;
    if (i < n) off[i] = incl[i] - deg[i] + bex[i / SCAN_B];
}

__global__ void edge_scatter(const int* __restrict__ ei, const int* __restrict__ off,
                             const int* __restrict__ rank, int* __restrict__ csr_src)
{
    for (int e = blockIdx.x * blockDim.x + threadIdx.x; e < E_TOT; e += gridDim.x * blockDim.x) {
        int s = (e < E_EDGES) ? ei[e] : (e - E_EDGES);
        int d = (e < E_EDGES) ? ei[E_EDGES + e] : (e - E_EDGES);
        csr_src[off[d] + rank[e]] = s;
    }
}

// ---------------- layer-1 aggregation: wave per node, fp8 payload (R6-frozen) ----------------
__global__ __launch_bounds__(256) void agg1_kernel(const unsigned char* __restrict__ h1b,
                                                   const int* __restrict__ csr_src,
                                                   const int* __restrict__ off,
                                                   const int* __restrict__ deg,
                                                   const float* __restrict__ a_src,
                                                   const float* __restrict__ a_dst,
                                                   const float* __restrict__ b1,
                                                   unsigned short* __restrict__ hEb)
{
    __shared__ int s_sh[4][72];
    __shared__ __align__(16) float ex_sh[4][72][4];
    const int wv = threadIdx.x >> 6, lane = threadIdx.x & 63;
    const int n = blockIdx.x * 4 + wv;
    if (n >= N_NODES) return;
    const int h = lane >> 4;
    const int st = off[n], cnt = deg[n];
    const float4 ad4 = *(const float4*)(a_dst + (size_t)n * 4);

    float4 acc = make_float4(0.f, 0.f, 0.f, 0.f);
    float dsum = 0.f;
    const unsigned char* __restrict__ hb = h1b + lane * 4;   // row stride = 256 B

    for (int cb = 0; cb < cnt; cb += 64) {
        const int c0 = st + cb;
        const int m = (cnt - cb < 64) ? (cnt - cb) : 64;

        // ---- phase A: lane-per-edge alpha computation ----
        {
            int s_l = csr_src[c0 + ((lane < m) ? lane : 0)];
            float4 as4 = *(const float4*)(a_src + (size_t)s_l * 4);
            float e0 = as4.x + ad4.x, e1 = as4.y + ad4.y,
                  e2 = as4.z + ad4.z, e3 = as4.w + ad4.w;
            e0 = (e0 > 0.f) ? e0 : NEG_SLOPE * e0;
            e1 = (e1 > 0.f) ? e1 : NEG_SLOPE * e1;
            e2 = (e2 > 0.f) ? e2 : NEG_SLOPE * e2;
            e3 = (e3 > 0.f) ? e3 : NEG_SLOPE * e3;
            float4 exv;
            exv.x = __expf(e0); exv.y = __expf(e1);
            exv.z = __expf(e2); exv.w = __expf(e3);
            if (lane < m) {
                s_sh[wv][lane] = s_l;
                *(float4*)&ex_sh[wv][lane][0] = exv;
            }
            if (lane < 8) {                       // ex=0 sentinel pad (valid src addr)
                s_sh[wv][m + lane] = csr_src[c0];
                *(float4*)&ex_sh[wv][m + lane][0] = make_float4(0.f, 0.f, 0.f, 0.f);
            }
        }
        // same-wave LDS write->read: compiler inserts lgkmcnt wait, no barrier

        // ---- phase B: payload gather (fp8) + weighted accumulate, depth-4 ----
        const int m4 = (m + 3) & ~3;
        int   sR0 = s_sh[wv][0], sR1 = s_sh[wv][1], sR2 = s_sh[wv][2], sR3 = s_sh[wv][3];
        float eR0 = ex_sh[wv][0][h], eR1 = ex_sh[wv][1][h],
              eR2 = ex_sh[wv][2][h], eR3 = ex_sh[wv][3][h];
        unsigned int vR0 = *(const unsigned int*)(hb + (size_t)sR0 * D1);
        unsigned int vR1 = *(const unsigned int*)(hb + (size_t)sR1 * D1);
        unsigned int vR2 = *(const unsigned int*)(hb + (size_t)sR2 * D1);
        unsigned int vR3 = *(const unsigned int*)(hb + (size_t)sR3 * D1);
        for (int j = 0; j < m4; j += 4) {
            int   sN0 = s_sh[wv][j + 4], sN1 = s_sh[wv][j + 5],
                  sN2 = s_sh[wv][j + 6], sN3 = s_sh[wv][j + 7];
            float eN0 = ex_sh[wv][j + 4][h], eN1 = ex_sh[wv][j + 5][h],
                  eN2 = ex_sh[wv][j + 6][h], eN3 = ex_sh[wv][j + 7][h];
            unsigned int vN0 = *(const unsigned int*)(hb + (size_t)sN0 * D1);
            unsigned int vN1 = *(const unsigned int*)(hb + (size_t)sN1 * D1);
            unsigned int vN2 = *(const unsigned int*)(hb + (size_t)sN2 * D1);
            unsigned int vN3 = *(const unsigned int*)(hb + (size_t)sN3 * D1);

            dsum += eR0;
            acc.x += eR0 * __builtin_amdgcn_cvt_f32_fp8((int)vR0, 0);
            acc.y += eR0 * __builtin_amdgcn_cvt_f32_fp8((int)vR0, 1);
            acc.z += eR0 * __builtin_amdgcn_cvt_f32_fp8((int)vR0, 2);
            acc.w += eR0 * __builtin_amdgcn_cvt_f32_fp8((int)vR0, 3);
            dsum += eR1;
            acc.x += eR1 * __builtin_amdgcn_cvt_f32_fp8((int)vR1, 0);
            acc.y += eR1 * __builtin_amdgcn_cvt_f32_fp8((int)vR1, 1);
            acc.z += eR1 * __builtin_amdgcn_cvt_f32_fp8((int)vR1, 2);
            acc.w += eR1 * __builtin_amdgcn_cvt_f32_fp8((int)vR1, 3);
            dsum += eR2;
            acc.x += eR2 * __builtin_amdgcn_cvt_f32_fp8((int)vR2, 0);
            acc.y += eR2 * __builtin_amdgcn_cvt_f32_fp8((int)vR2, 1);
            acc.z += eR2 * __builtin_amdgcn_cvt_f32_fp8((int)vR2, 2);
            acc.w += eR2 * __builtin_amdgcn_cvt_f32_fp8((int)vR2, 3);
            dsum += eR3;
            acc.x += eR3 * __builtin_amdgcn_cvt_f32_fp8((int)vR3, 0);
            acc.y += eR3 * __builtin_amdgcn_cvt_f32_fp8((int)vR3, 1);
            acc.z += eR3 * __builtin_amdgcn_cvt_f32_fp8((int)vR3, 2);
            acc.w += eR3 * __builtin_amdgcn_cvt_f32_fp8((int)vR3, 3);

            sR0 = sN0; sR1 = sN1; sR2 = sN2; sR3 = sN3;
            eR0 = eN0; eR1 = eN1; eR2 = eN2; eR3 = eN3;
            vR0 = vN0; vR1 = vN1; vR2 = vN2; vR3 = vN3;
        }
    }

    const float inv = 1.f / (dsum + 1e-16f);
    float4 bb = *(const float4*)(b1 + lane * 4);
    float ox = acc.x * inv + bb.x;
    float oy = acc.y * inv + bb.y;
    float oz = acc.z * inv + bb.z;
    float ow = acc.w * inv + bb.w;
    ox = (ox > 0.f) ? ox : expm1f(ox);
    oy = (oy > 0.f) ? oy : expm1f(oy);
    oz = (oz > 0.f) ? oz : expm1f(oz);
    ow = (ow > 0.f) ? ow : expm1f(ow);
    nus4 ob = { f2bf(ox), f2bf(oy), f2bf(oz), f2bf(ow) };
    __builtin_nontemporal_store(ob, (nus4*)(hEb + (size_t)n * D1 + lane * 4));
}

// ---------------- layer-2 aggregation: wave per node (R9-proven) ----------------
__global__ __launch_bounds__(256) void agg2_node_kernel(const unsigned short* __restrict__ h2b,
                                                        const int* __restrict__ csr_src,
                                                        const int* __restrict__ off,
                                                        const int* __restrict__ deg,
                                                        const float* __restrict__ a_src,
                                                        const float* __restrict__ a_dst,
                                                        const float* __restrict__ b2,
                                                        float* __restrict__ h3)
{
    __shared__ int   s_sh[4][96];
    __shared__ float ex_sh[4][96];
    const int wv = threadIdx.x >> 6, lane = threadIdx.x & 63;
    const int n = blockIdx.x * 4 + wv;
    if (n >= N_NODES) return;
    const int q = lane >> 4, ql = lane & 15;
    const int f0 = ql * 4;
    const int st = off[n], cnt = deg[n];
    const float adn = a_dst[n];
    const unsigned short* __restrict__ hb = h2b + f0;

    float4 acc = make_float4(0.f, 0.f, 0.f, 0.f);
    float dsum = 0.f;

    for (int cb = 0; cb < cnt; cb += 64) {
        const int c0 = st + cb;
        const int m = (cnt - cb < 64) ? (cnt - cb) : 64;

        // ---- phase A: lane-per-edge ex ----
        {
            int s_l = csr_src[c0 + ((lane < m) ? lane : 0)];
            float a = a_src[s_l] + adn;
            a = (a > 0.f) ? a : NEG_SLOPE * a;
            float ex = __expf(a);
            if (lane < m) { s_sh[wv][lane] = s_l; ex_sh[wv][lane] = ex; }
            int sb = __shfl(s_l, 0);
            if (lane < 32) { s_sh[wv][m + lane] = sb; ex_sh[wv][m + lane] = 0.f; }
        }

        // ---- phase B: quarter-wave per edge, depth-3 pipeline ----
        const int m4 = (m + 3) & ~3;
        int   sA = s_sh[wv][q],      sB = s_sh[wv][q + 4],  sC = s_sh[wv][q + 8];
        float eA = ex_sh[wv][q],     eB = ex_sh[wv][q + 4], eC = ex_sh[wv][q + 8];
        ushort4 vA = *(const ushort4*)(hb + (size_t)sA * HID);
        ushort4 vB = *(const ushort4*)(hb + (size_t)sB * HID);
        ushort4 vC = *(const ushort4*)(hb + (size_t)sC * HID);
        for (int j = 0; j < m4; j += 4) {
            int   sD = s_sh[wv][j + 12 + q];
            float eD = ex_sh[wv][j + 12 + q];
            ushort4 vD = *(const ushort4*)(hb + (size_t)sD * HID);

            dsum += eA;
            acc.x += eA * bf2f(vA.x); acc.y += eA * bf2f(vA.y);
            acc.z += eA * bf2f(vA.z); acc.w += eA * bf2f(vA.w);

            sA = sB; eA = eB; vA = vB;
            sB = sC; eB = eC; vB = vC;
            sC = sD; eC = eD; vC = vD;
        }
    }

    // reduce across quarters (lanes sharing ql)
    dsum  += __shfl_xor(dsum, 16);  dsum  += __shfl_xor(dsum, 32);
    acc.x += __shfl_xor(acc.x, 16); acc.x += __shfl_xor(acc.x, 32);
    acc.y += __shfl_xor(acc.y, 16); acc.y += __shfl_xor(acc.y, 32);
    acc.z += __shfl_xor(acc.z, 16); acc.z += __shfl_xor(acc.z, 32);
    acc.w += __shfl_xor(acc.w, 16); acc.w += __shfl_xor(acc.w, 32);

    const float inv = 1.f / (dsum + 1e-16f);
    const float4 bb = *(const float4*)(b2 + f0);
    float4 v;
    v.x = acc.x * inv + bb.x;
    v.y = acc.y * inv + bb.y;
    v.z = acc.z * inv + bb.z;
    v.w = acc.w * inv + bb.w;
    if (q == 0)
        __builtin_nontemporal_store(*(nfloat4*)&v, (nfloat4*)(h3 + (size_t)n * HID + f0));
}

// ---------------- streaming mean-pool: wave per node-chunk, lane per dim ----------------
__global__ __launch_bounds__(256) void pool_kernel(const float* __restrict__ h3,
                                                   const int* __restrict__ batch,
                                                   float* __restrict__ pool,
                                                   float* __restrict__ cntg,
                                                   int per)
{
    const int w = blockIdx.x * 4 + (threadIdx.x >> 6);
    const int lane = threadIdx.x & 63;
    const int n0 = w * per;
    if (n0 >= N_NODES) return;
    const int n1 = (n0 + per < N_NODES) ? n0 + per : N_NODES;

    float accv = 0.f, c = 0.f;
    int gcur = batch[n0];
    for (int n = n0; n < n1; ++n) {
        float v = h3[(size_t)n * HID + lane];
        int g = batch[n];
        if (g != gcur) {
#if defined(__AMDGCN__)
            unsafeAtomicAdd(&pool[gcur * HID + lane], accv);
            if (lane == 0) unsafeAtomicAdd(&cntg[gcur], c);
#else
            atomicAdd(&pool[gcur * HID + lane], accv);
            if (lane == 0) atomicAdd(&cntg[gcur], c);
#endif
            accv = 0.f; c = 0.f; gcur = g;
        }
        accv += v; c += 1.f;
    }
#if defined(__AMDGCN__)
    unsafeAtomicAdd(&pool[gcur * HID + lane], accv);
    if (lane == 0) unsafeAtomicAdd(&cntg[gcur], c);
#else
    atomicAdd(&pool[gcur * HID + lane], accv);
    if (lane == 0) atomicAdd(&cntg[gcur], c);
#endif
}

// ---------------- head: mean, relu MLP, logits (block per graph) ----------------
__global__ __launch_bounds__(64) void head_kernel(const float* __restrict__ pool,
                                                  const float* __restrict__ cntg,
                                                  const float* __restrict__ W3,
                                                  const float* __restrict__ b3,
                                                  const float* __restrict__ W4,
                                                  const float* __restrict__ b4,
                                                  float* __restrict__ out)
{
    const int g = blockIdx.x;
    const int lane = threadIdx.x;
    const float invc = 1.f / fmaxf(cntg[g], 1.f);
    float z = 0.f;
    if (lane < 32) {
        z = b3[lane];
        for (int k = 0; k < HID; ++k)
            z += pool[g * HID + k] * invc * W3[k * 32 + lane];
        z = fmaxf(z, 0.f);
    }
    float p0 = (lane < 32) ? z * W4[lane * 2 + 0] : 0.f;
    float p1 = (lane < 32) ? z * W4[lane * 2 + 1] : 0.f;
#pragma unroll
    for (int o = 1; o < 32; o <<= 1) { p0 += __shfl_xor(p0, o); p1 += __shfl_xor(p1, o); }
    if (lane == 0) { out[g * 2 + 0] = b4[0] + p0; out[g * 2 + 1] = b4[1] + p1; }
}

extern "C" void kernel_launch(void* const* d_in, const int* in_sizes, int n_in,
                              void* d_out, int out_size, void* d_ws, size_t ws_size,
                              hipStream_t stream)
{
    const float* x     = (const float*)d_in[0];
    const int*   ei    = (const int*)d_in[1];
    const int*   batch = (const int*)d_in[2];
    const float* W1    = (const float*)d_in[3];
    const float* as1w  = (const float*)d_in[4];
    const float* ad1w  = (const float*)d_in[5];
    const float* b1    = (const float*)d_in[6];
    const float* W2    = (const float*)d_in[7];
    const float* as2w  = (const float*)d_in[8];
    const float* ad2w  = (const float*)d_in[9];
    const float* b2    = (const float*)d_in[10];
    const float* W3    = (const float*)d_in[11];
    const float* b3    = (const float*)d_in[12];
    const float* W4    = (const float*)d_in[13];
    const float* b4    = (const float*)d_in[14];
    float* out = (float*)d_out;

    char* ws = (char*)d_ws;
    size_t o = 0;
    auto alloc = [&](size_t bytes) -> void* {
        void* p = ws + o;
        o += (bytes + 255) & ~(size_t)255;
        return p;
    };
    unsigned char*  h1b = (unsigned char*)alloc((size_t)N_NODES * D1);       // fp8 payload
    unsigned short* hEb = (unsigned short*)alloc((size_t)N_NODES * D1 * 2);
    unsigned short* h2b = (unsigned short*)alloc((size_t)N_NODES * HID * 2);
    float* h3   = (float*)alloc((size_t)N_NODES * HID * 4);                  // fp32 node results
    float* a_s1 = (float*)alloc((size_t)N_NODES * 4 * 4);
    float* a_d1 = (float*)alloc((size_t)N_NODES * 4 * 4);
    float* a_s2 = (float*)alloc((size_t)N_NODES * 4);
    float* a_d2 = (float*)alloc((size_t)N_NODES * 4);
    // deg/pool/cntg contiguous -> single memset
    char*  zbase  = (char*)alloc((size_t)N_NODES * 4 + G_GRAPHS * HID * 4 + G_GRAPHS * 4 + 1024);
    int*   deg    = (int*)zbase;
    float* pool   = (float*)(zbase + (((size_t)N_NODES * 4 + 255) & ~(size_t)255));
    float* cntg   = (float*)((char*)pool + (((size_t)G_GRAPHS * HID * 4 + 255) & ~(size_t)255));
    size_t zspan  = (char*)(cntg + G_GRAPHS) - zbase;
    int*   incl   = (int*)alloc((size_t)N_NODES * 4);
    int*   offv   = (int*)alloc((size_t)N_NODES * 4);
    int*   rank   = (int*)alloc((size_t)E_TOT * 4);
    int*   bsum   = (int*)alloc(128 * 4);
    int*   bex    = (int*)alloc(128 * 4);
    int*   csr    = (int*)alloc((size_t)E_TOT * 4);
    unsigned short* Wpk1 = (unsigned short*)alloc((size_t)32 * D1 * 8 * 2);   // 128 KB
    unsigned short* Wpk2 = (unsigned short*)alloc((size_t)32 * HID * 8 * 2);  // 32 KB

    (void)hipMemsetAsync(zbase, 0, zspan, stream);

    const int nblk_nodes = (N_NODES + 3) / 4;
    const int nscan = (N_NODES + SCAN_B - 1) / SCAN_B;
    const int ngemm = (N_NODES + 63) / 64;          // 64 rows per block (4 waves x 16)

    // pre-pack both weight matrices, one launch
    convW2x<<<(32 * D1 + 32 * HID + 255) / 256, 256, 0, stream>>>(W1, Wpk1, W2, Wpk2);

    // GEMM1 + att1: direct MFMA, column-split (wave = 16 rows x 64 cols)
    gemm_direct<D1, 64, false, true><<<dim3(ngemm, 4), 256, 0, stream>>>(
        x, Wpk1, h1b, as1w, ad1w, a_s1, a_d1, 4);

    // CSR build: hist records per-edge rank -> scatter is atomic-free
    edge_hist<<<4096, 256, 0, stream>>>(ei, deg, rank);
    scan_block<<<nscan, SCAN_B, 0, stream>>>(deg, incl, bsum, N_NODES);
    scan_bsum<<<1, 128, 0, stream>>>(bsum, bex, nscan);
    finalize_off<<<(N_NODES + 255) / 256, 256, 0, stream>>>(deg, incl, bex, offv, N_NODES);
    edge_scatter<<<4096, 256, 0, stream>>>(ei, offv, rank, csr);

    // layer-1 gather-aggregate (fp8 payload), fused softmax + b1 + ELU, bf16 out
    agg1_kernel<<<nblk_nodes, 256, 0, stream>>>(h1b, csr, offv, deg, a_s1, a_d1, b1, hEb);

    // GEMM2 + att2: direct MFMA (64 cols = one wave-group already)
    gemm_direct<HID, 64, true, false><<<dim3(ngemm, 1), 256, 0, stream>>>(
        hEb, Wpk2, h2b, as2w, ad2w, a_s2, a_d2, 1);

    // layer-2 gather-aggregate: wave per node (agg1's TLP shape), fp32 out
    agg2_node_kernel<<<nblk_nodes, 256, 0, stream>>>(h2b, csr, offv, deg, a_s2, a_d2, b2, h3);

    // streaming mean-pool over h3
    const int npool_blk = 512;                       // 2048 waves
    const int per = (N_NODES + npool_blk * 4 - 1) / (npool_blk * 4);
    pool_kernel<<<npool_blk, 256, 0, stream>>>(h3, batch, pool, cntg, per);

    // head MLP (block per graph)
    head_kernel<<<G_GRAPHS, 64, 0, stream>>>(pool, cntg, W3, b3, W4, b4, out);
}

// Round 12
// 545.964 us; speedup vs baseline: 1.0577x; 1.0577x over previous
//
#include <hip/hip_runtime.h>
#include <math.h>

#define N_NODES 100000
#define E_EDGES 1600000
#define E_TOT   (E_EDGES + N_NODES)
#define G_GRAPHS 64
#define IN_DIM 256
#define HID 64
#define HEADS 4
#define D1 256            // HEADS*HID
#define NEG_SLOPE 0.2f
#define SCAN_B 1024

typedef float nfloat4 __attribute__((ext_vector_type(4)));
typedef unsigned short nus4 __attribute__((ext_vector_type(4)));
typedef short bf16x8 __attribute__((ext_vector_type(8)));
typedef float f32x4 __attribute__((ext_vector_type(4)));

// bf16 <-> fp32
__device__ __forceinline__ float bf2f(unsigned short u) {
    unsigned int t = ((unsigned int)u) << 16;
    return __builtin_bit_cast(float, t);
}
__device__ __forceinline__ unsigned short f2bf(float f) {
    unsigned int u = __builtin_bit_cast(unsigned int, f);
    u += 0x7FFF + ((u >> 16) & 1);
    return (unsigned short)(u >> 16);
}
// pack 2 fp32 -> 2 bf16 in one dword (add-0x8000 round + v_perm)
__device__ __forceinline__ unsigned int pk2(float lo, float hi) {
    unsigned int ul = __builtin_bit_cast(unsigned int, lo) + 0x8000u;
    unsigned int uh = __builtin_bit_cast(unsigned int, hi) + 0x8000u;
    return __builtin_amdgcn_perm(uh, ul, 0x07060302u);
}

// ---------------- weight pre-pack (both layers, ONE launch) ----------------
__device__ __forceinline__ void packW(const float* __restrict__ W,
                                      unsigned short* __restrict__ Wpk, int Nc, int t)
{
    int kg = t / Nc, n = t - kg * Nc;
    const float* p = W + (size_t)(kg * 8) * Nc + n;
    uint4 v;
    v.x = pk2(p[0],      p[Nc]);
    v.y = pk2(p[2 * Nc], p[3 * Nc]);
    v.z = pk2(p[4 * Nc], p[5 * Nc]);
    v.w = pk2(p[6 * Nc], p[7 * Nc]);
    *(uint4*)(Wpk + (size_t)t * 8) = v;
}
__global__ __launch_bounds__(256) void convW2x(const float* __restrict__ W1,
                                               unsigned short* __restrict__ Wpk1,
                                               const float* __restrict__ W2,
                                               unsigned short* __restrict__ Wpk2)
{
    int t = blockIdx.x * 256 + threadIdx.x;
    if (t < 32 * D1) packW(W1, Wpk1, D1, t);
    else if (t < 32 * D1 + 32 * HID) packW(W2, Wpk2, HID, t - 32 * D1);
}

// ---------------- MFMA GEMM + fused attention dots (LDS-staged, R9-proven) ----------------
// BN=64: acc[2][4]=32 AGPR, ~5 blocks/CU resident -> barrier drains overlap.
// CFP8: C stored as fp8 e4m3 (agg1 gather payload); else bf16.
template<int BN, bool ABF16, bool CFP8>
__global__ __launch_bounds__(256) void gemm_mfma(const void* __restrict__ Ain,
                                                 const unsigned short* __restrict__ Wpk,
                                                 void* __restrict__ C,
                                                 int Nc,
                                                 const float* __restrict__ att_src,
                                                 const float* __restrict__ att_dst,
                                                 float* __restrict__ a_srcO,
                                                 float* __restrict__ a_dstO,
                                                 int astride)
{
    constexpr int NCG = BN / 16;                  // col-groups
    __shared__ unsigned short alds[2][4][128][8]; // 16 KB, double-buffered
    const int tid = threadIdx.x;
    const int lane = tid & 63, wv = tid >> 6;
    const int qd = lane >> 4, c16 = lane & 15;
    const int bm = blockIdx.y * 128, bn = blockIdx.x * BN;

    f32x4 acc[2][NCG];
#pragma unroll
    for (int i = 0; i < 2; ++i)
#pragma unroll
        for (int j = 0; j < NCG; ++j) acc[i][j] = (f32x4){0.f, 0.f, 0.f, 0.f};

    const int ar = tid >> 1, akh = tid & 1;       // A staging: row, k-half
    const int gm = bm + ar;
    const bool mv = gm < N_NODES;

    // prefetch regs for A
    uint4 v0, v1;                                  // ABF16 path
    float4 f0, f1, f2, f3;                         // fp32 path
    if (ABF16) {
        const unsigned short* Ab = (const unsigned short*)Ain + (size_t)gm * 256 + akh * 16;
        v0 = mv ? *(const uint4*)Ab : make_uint4(0, 0, 0, 0);
        v1 = mv ? *(const uint4*)(Ab + 8) : make_uint4(0, 0, 0, 0);
    } else {
        const float* Af = (const float*)Ain + (size_t)gm * 256 + akh * 16;
        if (mv) { f0 = ((const float4*)Af)[0]; f1 = ((const float4*)Af)[1];
                  f2 = ((const float4*)Af)[2]; f3 = ((const float4*)Af)[3]; }
        else { f0 = f1 = f2 = f3 = make_float4(0.f, 0.f, 0.f, 0.f); }
    }

    for (int k0 = 0; k0 < 256; k0 += 32) {
        const int p = (k0 >> 5) & 1;
        if (ABF16) {
            *(uint4*)&alds[p][2 * akh][ar][0] = v0;
            *(uint4*)&alds[p][2 * akh + 1][ar][0] = v1;
        } else {
            uint4 p0 = make_uint4(pk2(f0.x, f0.y), pk2(f0.z, f0.w), pk2(f1.x, f1.y), pk2(f1.z, f1.w));
            uint4 p1 = make_uint4(pk2(f2.x, f2.y), pk2(f2.z, f2.w), pk2(f3.x, f3.y), pk2(f3.z, f3.w));
            *(uint4*)&alds[p][2 * akh][ar][0] = p0;
            *(uint4*)&alds[p][2 * akh + 1][ar][0] = p1;
        }
        __syncthreads();

        if (k0 + 32 < 256) {                      // prefetch next A k-chunk
            if (ABF16) {
                const unsigned short* Ab = (const unsigned short*)Ain + (size_t)gm * 256 + (k0 + 32) + akh * 16;
                v0 = mv ? *(const uint4*)Ab : make_uint4(0, 0, 0, 0);
                v1 = mv ? *(const uint4*)(Ab + 8) : make_uint4(0, 0, 0, 0);
            } else {
                const float* Af = (const float*)Ain + (size_t)gm * 256 + (k0 + 32) + akh * 16;
                if (mv) { f0 = ((const float4*)Af)[0]; f1 = ((const float4*)Af)[1];
                          f2 = ((const float4*)Af)[2]; f3 = ((const float4*)Af)[3]; }
            }
        }

        // B-fragments straight from pre-packed global (L2-hot)
        const unsigned short* Wq = Wpk + ((size_t)((k0 >> 3) + qd) * Nc + bn) * 8;
        bf16x8 af0 = *(const bf16x8*)&alds[p][qd][wv * 32 + c16][0];
        bf16x8 af1 = *(const bf16x8*)&alds[p][qd][wv * 32 + 16 + c16][0];
#pragma unroll
        for (int cg = 0; cg < NCG; ++cg) {
            bf16x8 bfr = *(const bf16x8*)(Wq + (size_t)(cg * 16 + c16) * 8);
            acc[0][cg] = __builtin_amdgcn_mfma_f32_16x16x32_bf16(af0, bfr, acc[0][cg], 0, 0, 0);
            acc[1][cg] = __builtin_amdgcn_mfma_f32_16x16x32_bf16(af1, bfr, acc[1][cg], 0, 0, 0);
        }
    }

    // ---- epilogue: attention dots (fp32 acc, exact) + C store ----
    float sv[NCG], dv[NCG];
#pragma unroll
    for (int cg = 0; cg < NCG; ++cg) {
        sv[cg] = att_src[bn + cg * 16 + c16];
        dv[cg] = att_dst[bn + cg * 16 + c16];
    }
#pragma unroll
    for (int rg = 0; rg < 2; ++rg) {
#pragma unroll
        for (int reg = 0; reg < 4; ++reg) {
            const int m = bm + wv * 32 + rg * 16 + qd * 4 + reg;
#pragma unroll
            for (int hh = 0; hh < NCG / 4; ++hh) {
                float ps = 0.f, pd = 0.f;
#pragma unroll
                for (int cg = 4 * hh; cg < 4 * hh + 4; ++cg) {
                    ps += acc[rg][cg][reg] * sv[cg];
                    pd += acc[rg][cg][reg] * dv[cg];
                }
#pragma unroll
                for (int o = 1; o < 16; o <<= 1) { ps += __shfl_xor(ps, o); pd += __shfl_xor(pd, o); }
                if (c16 == 0 && m < N_NODES) {
                    a_srcO[m * astride + (bn >> 6) + hh] = ps;
                    a_dstO[m * astride + (bn >> 6) + hh] = pd;
                }
            }
            if (m < N_NODES) {
#pragma unroll
                for (int cg = 0; cg < NCG; ++cg) {
                    float val = acc[rg][cg][reg];
                    if (CFP8) {
                        unsigned int q8 = (unsigned int)__builtin_amdgcn_cvt_pk_fp8_f32(val, val, 0, false);
                        ((unsigned char*)C)[(size_t)m * Nc + bn + cg * 16 + c16] = (unsigned char)q8;
                    } else {
                        ((unsigned short*)C)[(size_t)m * Nc + bn + cg * 16 + c16] = f2bf(val);
                    }
                }
            }
        }
    }
}

// ---------------- CSR build: histogram(+rank), scan, atomic-free scatter ----------------
__global__ void edge_hist(const int* __restrict__ ei, int* __restrict__ deg,
                          int* __restrict__ rank)
{
    for (int e = blockIdx.x * blockDim.x + threadIdx.x; e < E_TOT; e += gridDim.x * blockDim.x) {
        int d = (e < E_EDGES) ? ei[E_EDGES + e] : (e - E_EDGES);
        rank[e] = atomicAdd(&deg[d], 1);
    }
}

__global__ __launch_bounds__(SCAN_B) void scan_block(const int* __restrict__ deg,
                                                     int* __restrict__ incl,
                                                     int* __restrict__ bsum, int n)
{
    __shared__ int s[SCAN_B];
    int i = blockIdx.x * SCAN_B + threadIdx.x;
    int v = (i < n) ? deg[i] : 0;
    s[threadIdx.x] = v;
    __syncthreads();
    for (int off = 1; off < SCAN_B; off <<= 1) {
        int t = (threadIdx.x >= off) ? s[threadIdx.x - off] : 0;
        __syncthreads();
        s[threadIdx.x] += t;
        __syncthreads();
    }
    if (i < n) incl[i] = s[threadIdx.x];
    if (threadIdx.x == SCAN_B - 1) bsum[blockIdx.x] = s[SCAN_B - 1];
}

__global__ void scan_bsum(const int* __restrict__ bsum, int* __restrict__ bex, int nb)
{
    __shared__ int s[128];
    int i = threadIdx.x;
    int v = (i < nb) ? bsum[i] : 0;
    s[i] = v;
    __syncthreads();
    for (int off = 1; off < 128; off <<= 1) {
        int t = (i >= off) ? s[i - off] : 0;
        __syncthreads();
        s[i] += t;
        __syncthreads();
    }
    if (i < nb) bex[i] = s[i] - v;   // exclusive
}

__global__ void finalize_off(const int* __restrict__ deg, const int* __restrict__ incl,
                             const int* __restrict__ bex, int* __restrict__ off, int n)
{
    int i = blockIdx.x * blockDim.x + threadIdx.x;
    if (i < n) off[i] = incl[i] - deg[i] + bex[i / SCAN_B];
}

__global__ void edge_scatter(const int* __restrict__ ei, const int* __restrict__ off,
                             const int* __restrict__ rank, int* __restrict__ csr_src)
{
    for (int e = blockIdx.x * blockDim.x + threadIdx.x; e < E_TOT; e += gridDim.x * blockDim.x) {
        int s = (e < E_EDGES) ? ei[e] : (e - E_EDGES);
        int d = (e < E_EDGES) ? ei[E_EDGES + e] : (e - E_EDGES);
        csr_src[off[d] + rank[e]] = s;
    }
}

// ---------------- layer-1 aggregation: wave per node, fp8 payload (R6-frozen) ----------------
__global__ __launch_bounds__(256) void agg1_kernel(const unsigned char* __restrict__ h1b,
                                                   const int* __restrict__ csr_src,
                                                   const int* __restrict__ off,
                                                   const int* __restrict__ deg,
                                                   const float* __restrict__ a_src,
                                                   const float* __restrict__ a_dst,
                                                   const float* __restrict__ b1,
                                                   unsigned short* __restrict__ hEb)
{
    __shared__ int s_sh[4][72];
    __shared__ __align__(16) float ex_sh[4][72][4];
    const int wv = threadIdx.x >> 6, lane = threadIdx.x & 63;
    const int n = blockIdx.x * 4 + wv;
    if (n >= N_NODES) return;
    const int h = lane >> 4;
    const int st = off[n], cnt = deg[n];
    const float4 ad4 = *(const float4*)(a_dst + (size_t)n * 4);

    float4 acc = make_float4(0.f, 0.f, 0.f, 0.f);
    float dsum = 0.f;
    const unsigned char* __restrict__ hb = h1b + lane * 4;   // row stride = 256 B

    for (int cb = 0; cb < cnt; cb += 64) {
        const int c0 = st + cb;
        const int m = (cnt - cb < 64) ? (cnt - cb) : 64;

        // ---- phase A: lane-per-edge alpha computation ----
        {
            int s_l = csr_src[c0 + ((lane < m) ? lane : 0)];
            float4 as4 = *(const float4*)(a_src + (size_t)s_l * 4);
            float e0 = as4.x + ad4.x, e1 = as4.y + ad4.y,
                  e2 = as4.z + ad4.z, e3 = as4.w + ad4.w;
            e0 = (e0 > 0.f) ? e0 : NEG_SLOPE * e0;
            e1 = (e1 > 0.f) ? e1 : NEG_SLOPE * e1;
            e2 = (e2 > 0.f) ? e2 : NEG_SLOPE * e2;
            e3 = (e3 > 0.f) ? e3 : NEG_SLOPE * e3;
            float4 exv;
            exv.x = __expf(e0); exv.y = __expf(e1);
            exv.z = __expf(e2); exv.w = __expf(e3);
            if (lane < m) {
                s_sh[wv][lane] = s_l;
                *(float4*)&ex_sh[wv][lane][0] = exv;
            }
            if (lane < 8) {                       // ex=0 sentinel pad (valid src addr)
                s_sh[wv][m + lane] = csr_src[c0];
                *(float4*)&ex_sh[wv][m + lane][0] = make_float4(0.f, 0.f, 0.f, 0.f);
            }
        }
        // same-wave LDS write->read: compiler inserts lgkmcnt wait, no barrier

        // ---- phase B: payload gather (fp8) + weighted accumulate, depth-4 ----
        const int m4 = (m + 3) & ~3;
        int   sR0 = s_sh[wv][0], sR1 = s_sh[wv][1], sR2 = s_sh[wv][2], sR3 = s_sh[wv][3];
        float eR0 = ex_sh[wv][0][h], eR1 = ex_sh[wv][1][h],
              eR2 = ex_sh[wv][2][h], eR3 = ex_sh[wv][3][h];
        unsigned int vR0 = *(const unsigned int*)(hb + (size_t)sR0 * D1);
        unsigned int vR1 = *(const unsigned int*)(hb + (size_t)sR1 * D1);
        unsigned int vR2 = *(const unsigned int*)(hb + (size_t)sR2 * D1);
        unsigned int vR3 = *(const unsigned int*)(hb + (size_t)sR3 * D1);
        for (int j = 0; j < m4; j += 4) {
            int   sN0 = s_sh[wv][j + 4], sN1 = s_sh[wv][j + 5],
                  sN2 = s_sh[wv][j + 6], sN3 = s_sh[wv][j + 7];
            float eN0 = ex_sh[wv][j + 4][h], eN1 = ex_sh[wv][j + 5][h],
                  eN2 = ex_sh[wv][j + 6][h], eN3 = ex_sh[wv][j + 7][h];
            unsigned int vN0 = *(const unsigned int*)(hb + (size_t)sN0 * D1);
            unsigned int vN1 = *(const unsigned int*)(hb + (size_t)sN1 * D1);
            unsigned int vN2 = *(const unsigned int*)(hb + (size_t)sN2 * D1);
            unsigned int vN3 = *(const unsigned int*)(hb + (size_t)sN3 * D1);

            dsum += eR0;
            acc.x += eR0 * __builtin_amdgcn_cvt_f32_fp8((int)vR0, 0);
            acc.y += eR0 * __builtin_amdgcn_cvt_f32_fp8((int)vR0, 1);
            acc.z += eR0 * __builtin_amdgcn_cvt_f32_fp8((int)vR0, 2);
            acc.w += eR0 * __builtin_amdgcn_cvt_f32_fp8((int)vR0, 3);
            dsum += eR1;
            acc.x += eR1 * __builtin_amdgcn_cvt_f32_fp8((int)vR1, 0);
            acc.y += eR1 * __builtin_amdgcn_cvt_f32_fp8((int)vR1, 1);
            acc.z += eR1 * __builtin_amdgcn_cvt_f32_fp8((int)vR1, 2);
            acc.w += eR1 * __builtin_amdgcn_cvt_f32_fp8((int)vR1, 3);
            dsum += eR2;
            acc.x += eR2 * __builtin_amdgcn_cvt_f32_fp8((int)vR2, 0);
            acc.y += eR2 * __builtin_amdgcn_cvt_f32_fp8((int)vR2, 1);
            acc.z += eR2 * __builtin_amdgcn_cvt_f32_fp8((int)vR2, 2);
            acc.w += eR2 * __builtin_amdgcn_cvt_f32_fp8((int)vR2, 3);
            dsum += eR3;
            acc.x += eR3 * __builtin_amdgcn_cvt_f32_fp8((int)vR3, 0);
            acc.y += eR3 * __builtin_amdgcn_cvt_f32_fp8((int)vR3, 1);
            acc.z += eR3 * __builtin_amdgcn_cvt_f32_fp8((int)vR3, 2);
            acc.w += eR3 * __builtin_amdgcn_cvt_f32_fp8((int)vR3, 3);

            sR0 = sN0; sR1 = sN1; sR2 = sN2; sR3 = sN3;
            eR0 = eN0; eR1 = eN1; eR2 = eN2; eR3 = eN3;
            vR0 = vN0; vR1 = vN1; vR2 = vN2; vR3 = vN3;
        }
    }

    const float inv = 1.f / (dsum + 1e-16f);
    float4 bb = *(const float4*)(b1 + lane * 4);
    float ox = acc.x * inv + bb.x;
    float oy = acc.y * inv + bb.y;
    float oz = acc.z * inv + bb.z;
    float ow = acc.w * inv + bb.w;
    ox = (ox > 0.f) ? ox : expm1f(ox);
    oy = (oy > 0.f) ? oy : expm1f(oy);
    oz = (oz > 0.f) ? oz : expm1f(oz);
    ow = (ow > 0.f) ? ow : expm1f(ow);
    nus4 ob = { f2bf(ox), f2bf(oy), f2bf(oz), f2bf(ow) };
    __builtin_nontemporal_store(ob, (nus4*)(hEb + (size_t)n * D1 + lane * 4));
}

// ---------------- layer-2 aggregation: wave per node (R9-proven) ----------------
__global__ __launch_bounds__(256) void agg2_node_kernel(const unsigned short* __restrict__ h2b,
                                                        const int* __restrict__ csr_src,
                                                        const int* __restrict__ off,
                                                        const int* __restrict__ deg,
                                                        const float* __restrict__ a_src,
                                                        const float* __restrict__ a_dst,
                                                        const float* __restrict__ b2,
                                                        float* __restrict__ h3)
{
    __shared__ int   s_sh[4][96];
    __shared__ float ex_sh[4][96];
    const int wv = threadIdx.x >> 6, lane = threadIdx.x & 63;
    const int n = blockIdx.x * 4 + wv;
    if (n >= N_NODES) return;
    const int q = lane >> 4, ql = lane & 15;
    const int f0 = ql * 4;
    const int st = off[n], cnt = deg[n];
    const float adn = a_dst[n];
    const unsigned short* __restrict__ hb = h2b + f0;

    float4 acc = make_float4(0.f, 0.f, 0.f, 0.f);
    float dsum = 0.f;

    for (int cb = 0; cb < cnt; cb += 64) {
        const int c0 = st + cb;
        const int m = (cnt - cb < 64) ? (cnt - cb) : 64;

        // ---- phase A: lane-per-edge ex ----
        {
            int s_l = csr_src[c0 + ((lane < m) ? lane : 0)];
            float a = a_src[s_l] + adn;
            a = (a > 0.f) ? a : NEG_SLOPE * a;
            float ex = __expf(a);
            if (lane < m) { s_sh[wv][lane] = s_l; ex_sh[wv][lane] = ex; }
            int sb = __shfl(s_l, 0);
            if (lane < 32) { s_sh[wv][m + lane] = sb; ex_sh[wv][m + lane] = 0.f; }
        }

        // ---- phase B: quarter-wave per edge, depth-3 pipeline ----
        const int m4 = (m + 3) & ~3;
        int   sA = s_sh[wv][q],      sB = s_sh[wv][q + 4],  sC = s_sh[wv][q + 8];
        float eA = ex_sh[wv][q],     eB = ex_sh[wv][q + 4], eC = ex_sh[wv][q + 8];
        ushort4 vA = *(const ushort4*)(hb + (size_t)sA * HID);
        ushort4 vB = *(const ushort4*)(hb + (size_t)sB * HID);
        ushort4 vC = *(const ushort4*)(hb + (size_t)sC * HID);
        for (int j = 0; j < m4; j += 4) {
            int   sD = s_sh[wv][j + 12 + q];
            float eD = ex_sh[wv][j + 12 + q];
            ushort4 vD = *(const ushort4*)(hb + (size_t)sD * HID);

            dsum += eA;
            acc.x += eA * bf2f(vA.x); acc.y += eA * bf2f(vA.y);
            acc.z += eA * bf2f(vA.z); acc.w += eA * bf2f(vA.w);

            sA = sB; eA = eB; vA = vB;
            sB = sC; eB = eC; vB = vC;
            sC = sD; eC = eD; vC = vD;
        }
    }

    // reduce across quarters (lanes sharing ql)
    dsum  += __shfl_xor(dsum, 16);  dsum  += __shfl_xor(dsum, 32);
    acc.x += __shfl_xor(acc.x, 16); acc.x += __shfl_xor(acc.x, 32);
    acc.y += __shfl_xor(acc.y, 16); acc.y += __shfl_xor(acc.y, 32);
    acc.z += __shfl_xor(acc.z, 16); acc.z += __shfl_xor(acc.z, 32);
    acc.w += __shfl_xor(acc.w, 16); acc.w += __shfl_xor(acc.w, 32);

    const float inv = 1.f / (dsum + 1e-16f);
    const float4 bb = *(const float4*)(b2 + f0);
    float4 v;
    v.x = acc.x * inv + bb.x;
    v.y = acc.y * inv + bb.y;
    v.z = acc.z * inv + bb.z;
    v.w = acc.w * inv + bb.w;
    if (q == 0)
        __builtin_nontemporal_store(*(nfloat4*)&v, (nfloat4*)(h3 + (size_t)n * HID + f0));
}

// ---------------- streaming mean-pool: wave per node-chunk, lane per dim ----------------
__global__ __launch_bounds__(256) void pool_kernel(const float* __restrict__ h3,
                                                   const int* __restrict__ batch,
                                                   float* __restrict__ pool,
                                                   float* __restrict__ cntg,
                                                   int per)
{
    const int w = blockIdx.x * 4 + (threadIdx.x >> 6);
    const int lane = threadIdx.x & 63;
    const int n0 = w * per;
    if (n0 >= N_NODES) return;
    const int n1 = (n0 + per < N_NODES) ? n0 + per : N_NODES;

    float accv = 0.f, c = 0.f;
    int gcur = batch[n0];
    for (int n = n0; n < n1; ++n) {
        float v = h3[(size_t)n * HID + lane];
        int g = batch[n];
        if (g != gcur) {
#if defined(__AMDGCN__)
            unsafeAtomicAdd(&pool[gcur * HID + lane], accv);
            if (lane == 0) unsafeAtomicAdd(&cntg[gcur], c);
#else
            atomicAdd(&pool[gcur * HID + lane], accv);
            if (lane == 0) atomicAdd(&cntg[gcur], c);
#endif
            accv = 0.f; c = 0.f; gcur = g;
        }
        accv += v; c += 1.f;
    }
#if defined(__AMDGCN__)
    unsafeAtomicAdd(&pool[gcur * HID + lane], accv);
    if (lane == 0) unsafeAtomicAdd(&cntg[gcur], c);
#else
    atomicAdd(&pool[gcur * HID + lane], accv);
    if (lane == 0) atomicAdd(&cntg[gcur], c);
#endif
}

// ---------------- head: mean, relu MLP, logits (block per graph) ----------------
__global__ __launch_bounds__(64) void head_kernel(const float* __restrict__ pool,
                                                  const float* __restrict__ cntg,
                                                  const float* __restrict__ W3,
                                                  const float* __restrict__ b3,
                                                  const float* __restrict__ W4,
                                                  const float* __restrict__ b4,
                                                  float* __restrict__ out)
{
    const int g = blockIdx.x;
    const int lane = threadIdx.x;
    const float invc = 1.f / fmaxf(cntg[g], 1.f);
    float z = 0.f;
    if (lane < 32) {
        z = b3[lane];
        for (int k = 0; k < HID; ++k)
            z += pool[g * HID + k] * invc * W3[k * 32 + lane];
        z = fmaxf(z, 0.f);
    }
    float p0 = (lane < 32) ? z * W4[lane * 2 + 0] : 0.f;
    float p1 = (lane < 32) ? z * W4[lane * 2 + 1] : 0.f;
#pragma unroll
    for (int o = 1; o < 32; o <<= 1) { p0 += __shfl_xor(p0, o); p1 += __shfl_xor(p1, o); }
    if (lane == 0) { out[g * 2 + 0] = b4[0] + p0; out[g * 2 + 1] = b4[1] + p1; }
}

extern "C" void kernel_launch(void* const* d_in, const int* in_sizes, int n_in,
                              void* d_out, int out_size, void* d_ws, size_t ws_size,
                              hipStream_t stream)
{
    const float* x     = (const float*)d_in[0];
    const int*   ei    = (const int*)d_in[1];
    const int*   batch = (const int*)d_in[2];
    const float* W1    = (const float*)d_in[3];
    const float* as1w  = (const float*)d_in[4];
    const float* ad1w  = (const float*)d_in[5];
    const float* b1    = (const float*)d_in[6];
    const float* W2    = (const float*)d_in[7];
    const float* as2w  = (const float*)d_in[8];
    const float* ad2w  = (const float*)d_in[9];
    const float* b2    = (const float*)d_in[10];
    const float* W3    = (const float*)d_in[11];
    const float* b3    = (const float*)d_in[12];
    const float* W4    = (const float*)d_in[13];
    const float* b4    = (const float*)d_in[14];
    float* out = (float*)d_out;

    char* ws = (char*)d_ws;
    size_t o = 0;
    auto alloc = [&](size_t bytes) -> void* {
        void* p = ws + o;
        o += (bytes + 255) & ~(size_t)255;
        return p;
    };
    unsigned char*  h1b = (unsigned char*)alloc((size_t)N_NODES * D1);       // fp8 payload
    unsigned short* hEb = (unsigned short*)alloc((size_t)N_NODES * D1 * 2);
    unsigned short* h2b = (unsigned short*)alloc((size_t)N_NODES * HID * 2);
    float* h3   = (float*)alloc((size_t)N_NODES * HID * 4);                  // fp32 node results
    float* a_s1 = (float*)alloc((size_t)N_NODES * 4 * 4);
    float* a_d1 = (float*)alloc((size_t)N_NODES * 4 * 4);
    float* a_s2 = (float*)alloc((size_t)N_NODES * 4);
    float* a_d2 = (float*)alloc((size_t)N_NODES * 4);
    // deg/pool/cntg contiguous -> single memset
    char*  zbase  = (char*)alloc((size_t)N_NODES * 4 + G_GRAPHS * HID * 4 + G_GRAPHS * 4 + 1024);
    int*   deg    = (int*)zbase;
    float* pool   = (float*)(zbase + (((size_t)N_NODES * 4 + 255) & ~(size_t)255));
    float* cntg   = (float*)((char*)pool + (((size_t)G_GRAPHS * HID * 4 + 255) & ~(size_t)255));
    size_t zspan  = (char*)(cntg + G_GRAPHS) - zbase;
    int*   incl   = (int*)alloc((size_t)N_NODES * 4);
    int*   offv   = (int*)alloc((size_t)N_NODES * 4);
    int*   rank   = (int*)alloc((size_t)E_TOT * 4);
    int*   bsum   = (int*)alloc(128 * 4);
    int*   bex    = (int*)alloc(128 * 4);
    int*   csr    = (int*)alloc((size_t)E_TOT * 4);
    unsigned short* Wpk1 = (unsigned short*)alloc((size_t)32 * D1 * 8 * 2);   // 128 KB
    unsigned short* Wpk2 = (unsigned short*)alloc((size_t)32 * HID * 8 * 2);  // 32 KB

    (void)hipMemsetAsync(zbase, 0, zspan, stream);

    const int nblk_nodes = (N_NODES + 3) / 4;
    const int nscan = (N_NODES + SCAN_B - 1) / SCAN_B;
    const int nrowblk = (N_NODES + 127) / 128;

    // pre-pack both weight matrices, one launch
    convW2x<<<(32 * D1 + 32 * HID + 255) / 256, 256, 0, stream>>>(W1, Wpk1, W2, Wpk2);

    // GEMM1 + att1 (MFMA, LDS-staged): h1b = fp8(bf16(x) @ Wpk1), 4 col-tiles of 64
    gemm_mfma<64, false, true><<<dim3(4, nrowblk), 256, 0, stream>>>(
        x, Wpk1, h1b, D1, as1w, ad1w, a_s1, a_d1, 4);

    // CSR build: hist records per-edge rank -> scatter is atomic-free
    edge_hist<<<4096, 256, 0, stream>>>(ei, deg, rank);
    scan_block<<<nscan, SCAN_B, 0, stream>>>(deg, incl, bsum, N_NODES);
    scan_bsum<<<1, 128, 0, stream>>>(bsum, bex, nscan);
    finalize_off<<<(N_NODES + 255) / 256, 256, 0, stream>>>(deg, incl, bex, offv, N_NODES);
    edge_scatter<<<4096, 256, 0, stream>>>(ei, offv, rank, csr);

    // layer-1 gather-aggregate (fp8 payload), fused softmax + b1 + ELU, bf16 out
    agg1_kernel<<<nblk_nodes, 256, 0, stream>>>(h1b, csr, offv, deg, a_s1, a_d1, b1, hEb);

    // GEMM2 + att2 (MFMA, LDS-staged): h2b = hEb @ Wpk2, single 64-col tile (bf16 C)
    gemm_mfma<64, true, false><<<dim3(1, nrowblk), 256, 0, stream>>>(
        hEb, Wpk2, h2b, HID, as2w, ad2w, a_s2, a_d2, 1);

    // layer-2 gather-aggregate: wave per node (agg1's TLP shape), fp32 out
    agg2_node_kernel<<<nblk_nodes, 256, 0, stream>>>(h2b, csr, offv, deg, a_s2, a_d2, b2, h3);

    // streaming mean-pool over h3
    const int npool_blk = 512;                       // 2048 waves
    const int per = (N_NODES + npool_blk * 4 - 1) / (npool_blk * 4);
    pool_kernel<<<npool_blk, 256, 0, stream>>>(h3, batch, pool, cntg, per);

    // head MLP (block per graph)
    head_kernel<<<G_GRAPHS, 64, 0, stream>>>(pool, cntg, W3, b3, W4, b4, out);
}

// Round 13
// 545.807 us; speedup vs baseline: 1.0580x; 1.0003x over previous
//
#include <hip/hip_runtime.h>
#include <math.h>

#define N_NODES 100000
#define E_EDGES 1600000
#define E_TOT   (E_EDGES + N_NODES)
#define G_GRAPHS 64
#define IN_DIM 256
#define HID 64
#define HEADS 4
#define D1 256            // HEADS*HID
#define NEG_SLOPE 0.2f
#define SCAN_B 1024

typedef float nfloat4 __attribute__((ext_vector_type(4)));
typedef unsigned short nus4 __attribute__((ext_vector_type(4)));
typedef short bf16x8 __attribute__((ext_vector_type(8)));
typedef float f32x4 __attribute__((ext_vector_type(4)));
typedef float f32x2 __attribute__((ext_vector_type(2)));

// bf16 <-> fp32
__device__ __forceinline__ float bf2f(unsigned short u) {
    unsigned int t = ((unsigned int)u) << 16;
    return __builtin_bit_cast(float, t);
}
__device__ __forceinline__ unsigned short f2bf(float f) {
    unsigned int u = __builtin_bit_cast(unsigned int, f);
    u += 0x7FFF + ((u >> 16) & 1);
    return (unsigned short)(u >> 16);
}
// pack 2 fp32 -> 2 bf16 in one dword (add-0x8000 round + v_perm)
__device__ __forceinline__ unsigned int pk2(float lo, float hi) {
    unsigned int ul = __builtin_bit_cast(unsigned int, lo) + 0x8000u;
    unsigned int uh = __builtin_bit_cast(unsigned int, hi) + 0x8000u;
    return __builtin_amdgcn_perm(uh, ul, 0x07060302u);
}

// ---------------- weight pre-pack (both layers, ONE launch) ----------------
__device__ __forceinline__ void packW(const float* __restrict__ W,
                                      unsigned short* __restrict__ Wpk, int Nc, int t)
{
    int kg = t / Nc, n = t - kg * Nc;
    const float* p = W + (size_t)(kg * 8) * Nc + n;
    uint4 v;
    v.x = pk2(p[0],      p[Nc]);
    v.y = pk2(p[2 * Nc], p[3 * Nc]);
    v.z = pk2(p[4 * Nc], p[5 * Nc]);
    v.w = pk2(p[6 * Nc], p[7 * Nc]);
    *(uint4*)(Wpk + (size_t)t * 8) = v;
}
__global__ __launch_bounds__(256) void convW2x(const float* __restrict__ W1,
                                               unsigned short* __restrict__ Wpk1,
                                               const float* __restrict__ W2,
                                               unsigned short* __restrict__ Wpk2)
{
    int t = blockIdx.x * 256 + threadIdx.x;
    if (t < 32 * D1) packW(W1, Wpk1, D1, t);
    else if (t < 32 * D1 + 32 * HID) packW(W2, Wpk2, HID, t - 32 * D1);
}

// ---------------- MFMA GEMM + fused attention dots (LDS-staged, R12 config) ----------------
template<int BN, bool ABF16, bool CFP8>
__global__ __launch_bounds__(256) void gemm_mfma(const void* __restrict__ Ain,
                                                 const unsigned short* __restrict__ Wpk,
                                                 void* __restrict__ C,
                                                 int Nc,
                                                 const float* __restrict__ att_src,
                                                 const float* __restrict__ att_dst,
                                                 float* __restrict__ a_srcO,
                                                 float* __restrict__ a_dstO,
                                                 int astride)
{
    constexpr int NCG = BN / 16;                  // col-groups
    __shared__ unsigned short alds[2][4][128][8]; // 16 KB, double-buffered
    const int tid = threadIdx.x;
    const int lane = tid & 63, wv = tid >> 6;
    const int qd = lane >> 4, c16 = lane & 15;
    const int bm = blockIdx.y * 128, bn = blockIdx.x * BN;

    f32x4 acc[2][NCG];
#pragma unroll
    for (int i = 0; i < 2; ++i)
#pragma unroll
        for (int j = 0; j < NCG; ++j) acc[i][j] = (f32x4){0.f, 0.f, 0.f, 0.f};

    const int ar = tid >> 1, akh = tid & 1;       // A staging: row, k-half
    const int gm = bm + ar;
    const bool mv = gm < N_NODES;

    // prefetch regs for A
    uint4 v0, v1;                                  // ABF16 path
    float4 f0, f1, f2, f3;                         // fp32 path
    if (ABF16) {
        const unsigned short* Ab = (const unsigned short*)Ain + (size_t)gm * 256 + akh * 16;
        v0 = mv ? *(const uint4*)Ab : make_uint4(0, 0, 0, 0);
        v1 = mv ? *(const uint4*)(Ab + 8) : make_uint4(0, 0, 0, 0);
    } else {
        const float* Af = (const float*)Ain + (size_t)gm * 256 + akh * 16;
        if (mv) { f0 = ((const float4*)Af)[0]; f1 = ((const float4*)Af)[1];
                  f2 = ((const float4*)Af)[2]; f3 = ((const float4*)Af)[3]; }
        else { f0 = f1 = f2 = f3 = make_float4(0.f, 0.f, 0.f, 0.f); }
    }

    for (int k0 = 0; k0 < 256; k0 += 32) {
        const int p = (k0 >> 5) & 1;
        if (ABF16) {
            *(uint4*)&alds[p][2 * akh][ar][0] = v0;
            *(uint4*)&alds[p][2 * akh + 1][ar][0] = v1;
        } else {
            uint4 p0 = make_uint4(pk2(f0.x, f0.y), pk2(f0.z, f0.w), pk2(f1.x, f1.y), pk2(f1.z, f1.w));
            uint4 p1 = make_uint4(pk2(f2.x, f2.y), pk2(f2.z, f2.w), pk2(f3.x, f3.y), pk2(f3.z, f3.w));
            *(uint4*)&alds[p][2 * akh][ar][0] = p0;
            *(uint4*)&alds[p][2 * akh + 1][ar][0] = p1;
        }
        __syncthreads();

        if (k0 + 32 < 256) {                      // prefetch next A k-chunk
            if (ABF16) {
                const unsigned short* Ab = (const unsigned short*)Ain + (size_t)gm * 256 + (k0 + 32) + akh * 16;
                v0 = mv ? *(const uint4*)Ab : make_uint4(0, 0, 0, 0);
                v1 = mv ? *(const uint4*)(Ab + 8) : make_uint4(0, 0, 0, 0);
            } else {
                const float* Af = (const float*)Ain + (size_t)gm * 256 + (k0 + 32) + akh * 16;
                if (mv) { f0 = ((const float4*)Af)[0]; f1 = ((const float4*)Af)[1];
                          f2 = ((const float4*)Af)[2]; f3 = ((const float4*)Af)[3]; }
            }
        }

        // B-fragments straight from pre-packed global (L2-hot)
        const unsigned short* Wq = Wpk + ((size_t)((k0 >> 3) + qd) * Nc + bn) * 8;
        bf16x8 af0 = *(const bf16x8*)&alds[p][qd][wv * 32 + c16][0];
        bf16x8 af1 = *(const bf16x8*)&alds[p][qd][wv * 32 + 16 + c16][0];
#pragma unroll
        for (int cg = 0; cg < NCG; ++cg) {
            bf16x8 bfr = *(const bf16x8*)(Wq + (size_t)(cg * 16 + c16) * 8);
            acc[0][cg] = __builtin_amdgcn_mfma_f32_16x16x32_bf16(af0, bfr, acc[0][cg], 0, 0, 0);
            acc[1][cg] = __builtin_amdgcn_mfma_f32_16x16x32_bf16(af1, bfr, acc[1][cg], 0, 0, 0);
        }
    }

    // ---- epilogue: attention dots (fp32 acc, exact) + C store ----
    float sv[NCG], dv[NCG];
#pragma unroll
    for (int cg = 0; cg < NCG; ++cg) {
        sv[cg] = att_src[bn + cg * 16 + c16];
        dv[cg] = att_dst[bn + cg * 16 + c16];
    }
#pragma unroll
    for (int rg = 0; rg < 2; ++rg) {
#pragma unroll
        for (int reg = 0; reg < 4; ++reg) {
            const int m = bm + wv * 32 + rg * 16 + qd * 4 + reg;
#pragma unroll
            for (int hh = 0; hh < NCG / 4; ++hh) {
                float ps = 0.f, pd = 0.f;
#pragma unroll
                for (int cg = 4 * hh; cg < 4 * hh + 4; ++cg) {
                    ps += acc[rg][cg][reg] * sv[cg];
                    pd += acc[rg][cg][reg] * dv[cg];
                }
#pragma unroll
                for (int o = 1; o < 16; o <<= 1) { ps += __shfl_xor(ps, o); pd += __shfl_xor(pd, o); }
                if (c16 == 0 && m < N_NODES) {
                    a_srcO[m * astride + (bn >> 6) + hh] = ps;
                    a_dstO[m * astride + (bn >> 6) + hh] = pd;
                }
            }
            if (m < N_NODES) {
#pragma unroll
                for (int cg = 0; cg < NCG; ++cg) {
                    float val = acc[rg][cg][reg];
                    if (CFP8) {
                        unsigned int q8 = (unsigned int)__builtin_amdgcn_cvt_pk_fp8_f32(val, val, 0, false);
                        ((unsigned char*)C)[(size_t)m * Nc + bn + cg * 16 + c16] = (unsigned char)q8;
                    } else {
                        ((unsigned short*)C)[(size_t)m * Nc + bn + cg * 16 + c16] = f2bf(val);
                    }
                }
            }
        }
    }
}

// ---------------- CSR build: histogram(+rank), scan, atomic-free scatter ----------------
__global__ void edge_hist(const int* __restrict__ ei, int* __restrict__ deg,
                          int* __restrict__ rank)
{
    for (int e = blockIdx.x * blockDim.x + threadIdx.x; e < E_TOT; e += gridDim.x * blockDim.x) {
        int d = (e < E_EDGES) ? ei[E_EDGES + e] : (e - E_EDGES);
        rank[e] = atomicAdd(&deg[d], 1);
    }
}

__global__ __launch_bounds__(SCAN_B) void scan_block(const int* __restrict__ deg,
                                                     int* __restrict__ incl,
                                                     int* __restrict__ bsum, int n)
{
    __shared__ int s[SCAN_B];
    int i = blockIdx.x * SCAN_B + threadIdx.x;
    int v = (i < n) ? deg[i] : 0;
    s[threadIdx.x] = v;
    __syncthreads();
    for (int off = 1; off < SCAN_B; off <<= 1) {
        int t = (threadIdx.x >= off) ? s[threadIdx.x - off] : 0;
        __syncthreads();
        s[threadIdx.x] += t;
        __syncthreads();
    }
    if (i < n) incl[i] = s[threadIdx.x];
    if (threadIdx.x == SCAN_B - 1) bsum[blockIdx.x] = s[SCAN_B - 1];
}

__global__ void scan_bsum(const int* __restrict__ bsum, int* __restrict__ bex, int nb)
{
    __shared__ int s[128];
    int i = threadIdx.x;
    int v = (i < nb) ? bsum[i] : 0;
    s[i] = v;
    __syncthreads();
    for (int off = 1; off < 128; off <<= 1) {
        int t = (i >= off) ? s[i - off] : 0;
        __syncthreads();
        s[i] += t;
        __syncthreads();
    }
    if (i < nb) bex[i] = s[i] - v;   // exclusive
}

__global__ void finalize_off(const int* __restrict__ deg, const int* __restrict__ incl,
                             const int* __restrict__ bex, int* __restrict__ off, int n)
{
    int i = blockIdx.x * blockDim.x + threadIdx.x;
    if (i < n) off[i] = incl[i] - deg[i] + bex[i / SCAN_B];
}

__global__ void edge_scatter(const int* __restrict__ ei, const int* __restrict__ off,
                             const int* __restrict__ rank, int* __restrict__ csr_src)
{
    for (int e = blockIdx.x * blockDim.x + threadIdx.x; e < E_TOT; e += gridDim.x * blockDim.x) {
        int s = (e < E_EDGES) ? ei[e] : (e - E_EDGES);
        int d = (e < E_EDGES) ? ei[E_EDGES + e] : (e - E_EDGES);
        csr_src[off[d] + rank[e]] = s;
    }
}

// ---------------- layer-1 aggregation: wave per node, fp8 payload ----------------
// Inner loop now uses v_cvt_pk_f32_fp8 (2 fp8 -> 2 f32 per VALU op): 9 -> 7 ops/edge,
// identical values + accumulation order -> bit-identical output.
__global__ __launch_bounds__(256) void agg1_kernel(const unsigned char* __restrict__ h1b,
                                                   const int* __restrict__ csr_src,
                                                   const int* __restrict__ off,
                                                   const int* __restrict__ deg,
                                                   const float* __restrict__ a_src,
                                                   const float* __restrict__ a_dst,
                                                   const float* __restrict__ b1,
                                                   unsigned short* __restrict__ hEb)
{
    __shared__ int s_sh[4][72];
    __shared__ __align__(16) float ex_sh[4][72][4];
    const int wv = threadIdx.x >> 6, lane = threadIdx.x & 63;
    const int n = blockIdx.x * 4 + wv;
    if (n >= N_NODES) return;
    const int h = lane >> 4;
    const int st = off[n], cnt = deg[n];
    const float4 ad4 = *(const float4*)(a_dst + (size_t)n * 4);

    float4 acc = make_float4(0.f, 0.f, 0.f, 0.f);
    float dsum = 0.f;
    const unsigned char* __restrict__ hb = h1b + lane * 4;   // row stride = 256 B

    for (int cb = 0; cb < cnt; cb += 64) {
        const int c0 = st + cb;
        const int m = (cnt - cb < 64) ? (cnt - cb) : 64;

        // ---- phase A: lane-per-edge alpha computation ----
        {
            int s_l = csr_src[c0 + ((lane < m) ? lane : 0)];
            float4 as4 = *(const float4*)(a_src + (size_t)s_l * 4);
            float e0 = as4.x + ad4.x, e1 = as4.y + ad4.y,
                  e2 = as4.z + ad4.z, e3 = as4.w + ad4.w;
            e0 = (e0 > 0.f) ? e0 : NEG_SLOPE * e0;
            e1 = (e1 > 0.f) ? e1 : NEG_SLOPE * e1;
            e2 = (e2 > 0.f) ? e2 : NEG_SLOPE * e2;
            e3 = (e3 > 0.f) ? e3 : NEG_SLOPE * e3;
            float4 exv;
            exv.x = __expf(e0); exv.y = __expf(e1);
            exv.z = __expf(e2); exv.w = __expf(e3);
            if (lane < m) {
                s_sh[wv][lane] = s_l;
                *(float4*)&ex_sh[wv][lane][0] = exv;
            }
            if (lane < 8) {                       // ex=0 sentinel pad (valid src addr)
                s_sh[wv][m + lane] = csr_src[c0];
                *(float4*)&ex_sh[wv][m + lane][0] = make_float4(0.f, 0.f, 0.f, 0.f);
            }
        }
        // same-wave LDS write->read: compiler inserts lgkmcnt wait, no barrier

        // ---- phase B: payload gather (fp8, packed cvt) + weighted accumulate, depth-4 ----
        const int m4 = (m + 3) & ~3;
        int   sR0 = s_sh[wv][0], sR1 = s_sh[wv][1], sR2 = s_sh[wv][2], sR3 = s_sh[wv][3];
        float eR0 = ex_sh[wv][0][h], eR1 = ex_sh[wv][1][h],
              eR2 = ex_sh[wv][2][h], eR3 = ex_sh[wv][3][h];
        unsigned int vR0 = *(const unsigned int*)(hb + (size_t)sR0 * D1);
        unsigned int vR1 = *(const unsigned int*)(hb + (size_t)sR1 * D1);
        unsigned int vR2 = *(const unsigned int*)(hb + (size_t)sR2 * D1);
        unsigned int vR3 = *(const unsigned int*)(hb + (size_t)sR3 * D1);
        for (int j = 0; j < m4; j += 4) {
            int   sN0 = s_sh[wv][j + 4], sN1 = s_sh[wv][j + 5],
                  sN2 = s_sh[wv][j + 6], sN3 = s_sh[wv][j + 7];
            float eN0 = ex_sh[wv][j + 4][h], eN1 = ex_sh[wv][j + 5][h],
                  eN2 = ex_sh[wv][j + 6][h], eN3 = ex_sh[wv][j + 7][h];
            unsigned int vN0 = *(const unsigned int*)(hb + (size_t)sN0 * D1);
            unsigned int vN1 = *(const unsigned int*)(hb + (size_t)sN1 * D1);
            unsigned int vN2 = *(const unsigned int*)(hb + (size_t)sN2 * D1);
            unsigned int vN3 = *(const unsigned int*)(hb + (size_t)sN3 * D1);

            {
                f32x2 lo = __builtin_amdgcn_cvt_pk_f32_fp8((int)vR0, false);
                f32x2 hi = __builtin_amdgcn_cvt_pk_f32_fp8((int)vR0, true);
                dsum += eR0;
                acc.x += eR0 * lo[0]; acc.y += eR0 * lo[1];
                acc.z += eR0 * hi[0]; acc.w += eR0 * hi[1];
            }
            {
                f32x2 lo = __builtin_amdgcn_cvt_pk_f32_fp8((int)vR1, false);
                f32x2 hi = __builtin_amdgcn_cvt_pk_f32_fp8((int)vR1, true);
                dsum += eR1;
                acc.x += eR1 * lo[0]; acc.y += eR1 * lo[1];
                acc.z += eR1 * hi[0]; acc.w += eR1 * hi[1];
            }
            {
                f32x2 lo = __builtin_amdgcn_cvt_pk_f32_fp8((int)vR2, false);
                f32x2 hi = __builtin_amdgcn_cvt_pk_f32_fp8((int)vR2, true);
                dsum += eR2;
                acc.x += eR2 * lo[0]; acc.y += eR2 * lo[1];
                acc.z += eR2 * hi[0]; acc.w += eR2 * hi[1];
            }
            {
                f32x2 lo = __builtin_amdgcn_cvt_pk_f32_fp8((int)vR3, false);
                f32x2 hi = __builtin_amdgcn_cvt_pk_f32_fp8((int)vR3, true);
                dsum += eR3;
                acc.x += eR3 * lo[0]; acc.y += eR3 * lo[1];
                acc.z += eR3 * hi[0]; acc.w += eR3 * hi[1];
            }

            sR0 = sN0; sR1 = sN1; sR2 = sN2; sR3 = sN3;
            eR0 = eN0; eR1 = eN1; eR2 = eN2; eR3 = eN3;
            vR0 = vN0; vR1 = vN1; vR2 = vN2; vR3 = vN3;
        }
    }

    const float inv = 1.f / (dsum + 1e-16f);
    float4 bb = *(const float4*)(b1 + lane * 4);
    float ox = acc.x * inv + bb.x;
    float oy = acc.y * inv + bb.y;
    float oz = acc.z * inv + bb.z;
    float ow = acc.w * inv + bb.w;
    ox = (ox > 0.f) ? ox : expm1f(ox);
    oy = (oy > 0.f) ? oy : expm1f(oy);
    oz = (oz > 0.f) ? oz : expm1f(oz);
    ow = (ow > 0.f) ? ow : expm1f(ow);
    nus4 ob = { f2bf(ox), f2bf(oy), f2bf(oz), f2bf(ow) };
    __builtin_nontemporal_store(ob, (nus4*)(hEb + (size_t)n * D1 + lane * 4));
}

// ---------------- layer-2 aggregation: wave per node (R9-proven) ----------------
__global__ __launch_bounds__(256) void agg2_node_kernel(const unsigned short* __restrict__ h2b,
                                                        const int* __restrict__ csr_src,
                                                        const int* __restrict__ off,
                                                        const int* __restrict__ deg,
                                                        const float* __restrict__ a_src,
                                                        const float* __restrict__ a_dst,
                                                        const float* __restrict__ b2,
                                                        float* __restrict__ h3)
{
    __shared__ int   s_sh[4][96];
    __shared__ float ex_sh[4][96];
    const int wv = threadIdx.x >> 6, lane = threadIdx.x & 63;
    const int n = blockIdx.x * 4 + wv;
    if (n >= N_NODES) return;
    const int q = lane >> 4, ql = lane & 15;
    const int f0 = ql * 4;
    const int st = off[n], cnt = deg[n];
    const float adn = a_dst[n];
    const unsigned short* __restrict__ hb = h2b + f0;

    float4 acc = make_float4(0.f, 0.f, 0.f, 0.f);
    float dsum = 0.f;

    for (int cb = 0; cb < cnt; cb += 64) {
        const int c0 = st + cb;
        const int m = (cnt - cb < 64) ? (cnt - cb) : 64;

        // ---- phase A: lane-per-edge ex ----
        {
            int s_l = csr_src[c0 + ((lane < m) ? lane : 0)];
            float a = a_src[s_l] + adn;
            a = (a > 0.f) ? a : NEG_SLOPE * a;
            float ex = __expf(a);
            if (lane < m) { s_sh[wv][lane] = s_l; ex_sh[wv][lane] = ex; }
            int sb = __shfl(s_l, 0);
            if (lane < 32) { s_sh[wv][m + lane] = sb; ex_sh[wv][m + lane] = 0.f; }
        }

        // ---- phase B: quarter-wave per edge, depth-3 pipeline ----
        const int m4 = (m + 3) & ~3;
        int   sA = s_sh[wv][q],      sB = s_sh[wv][q + 4],  sC = s_sh[wv][q + 8];
        float eA = ex_sh[wv][q],     eB = ex_sh[wv][q + 4], eC = ex_sh[wv][q + 8];
        ushort4 vA = *(const ushort4*)(hb + (size_t)sA * HID);
        ushort4 vB = *(const ushort4*)(hb + (size_t)sB * HID);
        ushort4 vC = *(const ushort4*)(hb + (size_t)sC * HID);
        for (int j = 0; j < m4; j += 4) {
            int   sD = s_sh[wv][j + 12 + q];
            float eD = ex_sh[wv][j + 12 + q];
            ushort4 vD = *(const ushort4*)(hb + (size_t)sD * HID);

            dsum += eA;
            acc.x += eA * bf2f(vA.x); acc.y += eA * bf2f(vA.y);
            acc.z += eA * bf2f(vA.z); acc.w += eA * bf2f(vA.w);

            sA = sB; eA = eB; vA = vB;
            sB = sC; eB = eC; vB = vC;
            sC = sD; eC = eD; vC = vD;
        }
    }

    // reduce across quarters (lanes sharing ql)
    dsum  += __shfl_xor(dsum, 16);  dsum  += __shfl_xor(dsum, 32);
    acc.x += __shfl_xor(acc.x, 16); acc.x += __shfl_xor(acc.x, 32);
    acc.y += __shfl_xor(acc.y, 16); acc.y += __shfl_xor(acc.y, 32);
    acc.z += __shfl_xor(acc.z, 16); acc.z += __shfl_xor(acc.z, 32);
    acc.w += __shfl_xor(acc.w, 16); acc.w += __shfl_xor(acc.w, 32);

    const float inv = 1.f / (dsum + 1e-16f);
    const float4 bb = *(const float4*)(b2 + f0);
    float4 v;
    v.x = acc.x * inv + bb.x;
    v.y = acc.y * inv + bb.y;
    v.z = acc.z * inv + bb.z;
    v.w = acc.w * inv + bb.w;
    if (q == 0)
        __builtin_nontemporal_store(*(nfloat4*)&v, (nfloat4*)(h3 + (size_t)n * HID + f0));
}

// ---------------- streaming mean-pool: wave per node-chunk, lane per dim ----------------
__global__ __launch_bounds__(256) void pool_kernel(const float* __restrict__ h3,
                                                   const int* __restrict__ batch,
                                                   float* __restrict__ pool,
                                                   float* __restrict__ cntg,
                                                   int per)
{
    const int w = blockIdx.x * 4 + (threadIdx.x >> 6);
    const int lane = threadIdx.x & 63;
    const int n0 = w * per;
    if (n0 >= N_NODES) return;
    const int n1 = (n0 + per < N_NODES) ? n0 + per : N_NODES;

    float accv = 0.f, c = 0.f;
    int gcur = batch[n0];
    for (int n = n0; n < n1; ++n) {
        float v = h3[(size_t)n * HID + lane];
        int g = batch[n];
        if (g != gcur) {
#if defined(__AMDGCN__)
            unsafeAtomicAdd(&pool[gcur * HID + lane], accv);
            if (lane == 0) unsafeAtomicAdd(&cntg[gcur], c);
#else
            atomicAdd(&pool[gcur * HID + lane], accv);
            if (lane == 0) atomicAdd(&cntg[gcur], c);
#endif
            accv = 0.f; c = 0.f; gcur = g;
        }
        accv += v; c += 1.f;
    }
#if defined(__AMDGCN__)
    unsafeAtomicAdd(&pool[gcur * HID + lane], accv);
    if (lane == 0) unsafeAtomicAdd(&cntg[gcur], c);
#else
    atomicAdd(&pool[gcur * HID + lane], accv);
    if (lane == 0) atomicAdd(&cntg[gcur], c);
#endif
}

// ---------------- head: mean, relu MLP, logits (block per graph) ----------------
__global__ __launch_bounds__(64) void head_kernel(const float* __restrict__ pool,
                                                  const float* __restrict__ cntg,
                                                  const float* __restrict__ W3,
                                                  const float* __restrict__ b3,
                                                  const float* __restrict__ W4,
                                                  const float* __restrict__ b4,
                                                  float* __restrict__ out)
{
    const int g = blockIdx.x;
    const int lane = threadIdx.x;
    const float invc = 1.f / fmaxf(cntg[g], 1.f);
    float z = 0.f;
    if (lane < 32) {
        z = b3[lane];
        for (int k = 0; k < HID; ++k)
            z += pool[g * HID + k] * invc * W3[k * 32 + lane];
        z = fmaxf(z, 0.f);
    }
    float p0 = (lane < 32) ? z * W4[lane * 2 + 0] : 0.f;
    float p1 = (lane < 32) ? z * W4[lane * 2 + 1] : 0.f;
#pragma unroll
    for (int o = 1; o < 32; o <<= 1) { p0 += __shfl_xor(p0, o); p1 += __shfl_xor(p1, o); }
    if (lane == 0) { out[g * 2 + 0] = b4[0] + p0; out[g * 2 + 1] = b4[1] + p1; }
}

extern "C" void kernel_launch(void* const* d_in, const int* in_sizes, int n_in,
                              void* d_out, int out_size, void* d_ws, size_t ws_size,
                              hipStream_t stream)
{
    const float* x     = (const float*)d_in[0];
    const int*   ei    = (const int*)d_in[1];
    const int*   batch = (const int*)d_in[2];
    const float* W1    = (const float*)d_in[3];
    const float* as1w  = (const float*)d_in[4];
    const float* ad1w  = (const float*)d_in[5];
    const float* b1    = (const float*)d_in[6];
    const float* W2    = (const float*)d_in[7];
    const float* as2w  = (const float*)d_in[8];
    const float* ad2w  = (const float*)d_in[9];
    const float* b2    = (const float*)d_in[10];
    const float* W3    = (const float*)d_in[11];
    const float* b3    = (const float*)d_in[12];
    const float* W4    = (const float*)d_in[13];
    const float* b4    = (const float*)d_in[14];
    float* out = (float*)d_out;

    char* ws = (char*)d_ws;
    size_t o = 0;
    auto alloc = [&](size_t bytes) -> void* {
        void* p = ws + o;
        o += (bytes + 255) & ~(size_t)255;
        return p;
    };
    unsigned char*  h1b = (unsigned char*)alloc((size_t)N_NODES * D1);       // fp8 payload
    unsigned short* hEb = (unsigned short*)alloc((size_t)N_NODES * D1 * 2);
    unsigned short* h2b = (unsigned short*)alloc((size_t)N_NODES * HID * 2);
    float* h3   = (float*)alloc((size_t)N_NODES * HID * 4);                  // fp32 node results
    float* a_s1 = (float*)alloc((size_t)N_NODES * 4 * 4);
    float* a_d1 = (float*)alloc((size_t)N_NODES * 4 * 4);
    float* a_s2 = (float*)alloc((size_t)N_NODES * 4);
    float* a_d2 = (float*)alloc((size_t)N_NODES * 4);
    // deg/pool/cntg contiguous -> single memset
    char*  zbase  = (char*)alloc((size_t)N_NODES * 4 + G_GRAPHS * HID * 4 + G_GRAPHS * 4 + 1024);
    int*   deg    = (int*)zbase;
    float* pool   = (float*)(zbase + (((size_t)N_NODES * 4 + 255) & ~(size_t)255));
    float* cntg   = (float*)((char*)pool + (((size_t)G_GRAPHS * HID * 4 + 255) & ~(size_t)255));
    size_t zspan  = (char*)(cntg + G_GRAPHS) - zbase;
    int*   incl   = (int*)alloc((size_t)N_NODES * 4);
    int*   offv   = (int*)alloc((size_t)N_NODES * 4);
    int*   rank   = (int*)alloc((size_t)E_TOT * 4);
    int*   bsum   = (int*)alloc(128 * 4);
    int*   bex    = (int*)alloc(128 * 4);
    int*   csr    = (int*)alloc((size_t)E_TOT * 4);
    unsigned short* Wpk1 = (unsigned short*)alloc((size_t)32 * D1 * 8 * 2);   // 128 KB
    unsigned short* Wpk2 = (unsigned short*)alloc((size_t)32 * HID * 8 * 2);  // 32 KB

    (void)hipMemsetAsync(zbase, 0, zspan, stream);

    const int nblk_nodes = (N_NODES + 3) / 4;
    const int nscan = (N_NODES + SCAN_B - 1) / SCAN_B;
    const int nrowblk = (N_NODES + 127) / 128;

    // pre-pack both weight matrices, one launch
    convW2x<<<(32 * D1 + 32 * HID + 255) / 256, 256, 0, stream>>>(W1, Wpk1, W2, Wpk2);

    // GEMM1 + att1 (MFMA, LDS-staged): h1b = fp8(bf16(x) @ Wpk1), 4 col-tiles of 64
    gemm_mfma<64, false, true><<<dim3(4, nrowblk), 256, 0, stream>>>(
        x, Wpk1, h1b, D1, as1w, ad1w, a_s1, a_d1, 4);

    // CSR build: hist records per-edge rank -> scatter is atomic-free
    edge_hist<<<4096, 256, 0, stream>>>(ei, deg, rank);
    scan_block<<<nscan, SCAN_B, 0, stream>>>(deg, incl, bsum, N_NODES);
    scan_bsum<<<1, 128, 0, stream>>>(bsum, bex, nscan);
    finalize_off<<<(N_NODES + 255) / 256, 256, 0, stream>>>(deg, incl, bex, offv, N_NODES);
    edge_scatter<<<4096, 256, 0, stream>>>(ei, offv, rank, csr);

    // layer-1 gather-aggregate (fp8 payload, packed cvt), fused softmax + b1 + ELU
    agg1_kernel<<<nblk_nodes, 256, 0, stream>>>(h1b, csr, offv, deg, a_s1, a_d1, b1, hEb);

    // GEMM2 + att2 (MFMA, LDS-staged): h2b = hEb @ Wpk2, single 64-col tile (bf16 C)
    gemm_mfma<64, true, false><<<dim3(1, nrowblk), 256, 0, stream>>>(
        hEb, Wpk2, h2b, HID, as2w, ad2w, a_s2, a_d2, 1);

    // layer-2 gather-aggregate: wave per node (agg1's TLP shape), fp32 out
    agg2_node_kernel<<<nblk_nodes, 256, 0, stream>>>(h2b, csr, offv, deg, a_s2, a_d2, b2, h3);

    // streaming mean-pool over h3
    const int npool_blk = 512;                       // 2048 waves
    const int per = (N_NODES + npool_blk * 4 - 1) / (npool_blk * 4);
    pool_kernel<<<npool_blk, 256, 0, stream>>>(h3, batch, pool, cntg, per);

    // head MLP (block per graph)
    head_kernel<<<G_GRAPHS, 64, 0, stream>>>(pool, cntg, W3, b3, W4, b4, out);
}